// Round 2
// baseline (135.254 us; speedup 1.0000x reference)
//
#include <hip/hip_runtime.h>
#include <math.h>

#define B 4
#define C 384
#define HIN 224
#define WIN 224
#define KS 14
#define HB 16
#define WBL 16
#define P 196        // KS*KS
#define HW (HIN * WIN)
#define CG 4         // channel groups in rowsum pass
#define CPG (C / CG) // 96 channels per group
#define NC 8         // channels per fused block

// ---------------------------------------------------------------------------
// Kernel 1 (per batch b): partial rowsum over one channel group.
// part[g][h][w] = sum_{c in group g} hr_b[c,h,w] * attn_w[c]
// Grid: HIN * CG blocks. Block: 256 threads (4 waves), lanes<56 hold float4.
// ---------------------------------------------------------------------------
__global__ __launch_bounds__(256) void k_rowsum_b(const float* __restrict__ hr_b,
                                                  const float* __restrict__ attn_w,
                                                  float* __restrict__ part) {
    __shared__ float wlds[CPG];
    __shared__ float4 red[224];
    const int blk = blockIdx.x;
    const int h = blk % HIN, g = blk / HIN;
    const int tid = threadIdx.x;
    if (tid < CPG) wlds[tid] = attn_w[g * CPG + tid];
    __syncthreads();

    const int wv = tid >> 6, lane = tid & 63;
    float4 acc = make_float4(0.f, 0.f, 0.f, 0.f);
    if (lane < 56) {
        const float* base = hr_b + (size_t)(g * CPG) * HW + (size_t)h * WIN + lane * 4;
        #pragma unroll 4
        for (int j = 0; j < CPG / 4; ++j) {
            const int cl = wv + 4 * j;
            const float4 v = *reinterpret_cast<const float4*>(base + (size_t)cl * HW);
            const float wc = wlds[cl];
            acc.x += v.x * wc; acc.y += v.y * wc; acc.z += v.z * wc; acc.w += v.w * wc;
        }
        red[wv * 56 + lane] = acc;
    }
    __syncthreads();
    if (tid < 56) {
        const float4 a0 = red[tid], a1 = red[56 + tid], a2 = red[112 + tid], a3 = red[168 + tid];
        float4 s;
        s.x = a0.x + a1.x + a2.x + a3.x;
        s.y = a0.y + a1.y + a2.y + a3.y;
        s.z = a0.z + a1.z + a2.z + a3.z;
        s.w = a0.w + a1.w + a2.w + a3.w;
        reinterpret_cast<float4*>(part + ((size_t)g * HIN + h) * WIN)[tid] = s;
    }
}

// ---------------------------------------------------------------------------
// Kernel 2 (per batch b): fused softmax + weighted patch reduction.
// One block per (hb, channel-chunk of NC). Recomputes the softmax for its
// (hb) strip from the 4 rowsum partials (unnormalized exp kept in LDS),
// then accumulates NC channels, dividing by the softmax denominator at the end.
// LDS layout for exp weights: e_lds[ki*224 + w], w = wb*14+kj  (== lane id).
// ---------------------------------------------------------------------------
__global__ __launch_bounds__(256) void k_fused_b(const float* __restrict__ hr_b,
                                                 const float* __restrict__ part,
                                                 const float* __restrict__ attn_b,
                                                 const float* __restrict__ w_kk,
                                                 const float* __restrict__ b_kk,
                                                 const int* __restrict__ mask_b,
                                                 float* __restrict__ out_b) {
    __shared__ float e_lds[KS * WIN];      // 3136
    __shared__ float wkk[P], bkk[P];
    __shared__ float colsum[2][WIN];
    __shared__ float wbmax[WBL], wbsum[WBL], maskv[WBL];
    const int hb = blockIdx.x & 15;
    const int cg = blockIdx.x >> 4;        // 0..47
    const int tid = threadIdx.x;

    if (tid < P) { wkk[tid] = w_kk[tid]; bkk[tid] = b_kk[tid]; }
    if (tid >= 224 && tid < 240) maskv[tid - 224] = mask_b[hb * WBL + (tid - 224)] ? 1.f : 0.f;
    __syncthreads();

    const float ab = attn_b[0];
    // logits into e_lds
    for (int i = tid; i < KS * WIN; i += 256) {
        const int ki = i / WIN, w = i % WIN;
        const int wb = w / KS, kj = w % KS;
        const float r = part[((size_t)0 * HIN + hb * KS + ki) * WIN + w]
                      + part[((size_t)1 * HIN + hb * KS + ki) * WIN + w]
                      + part[((size_t)2 * HIN + hb * KS + ki) * WIN + w]
                      + part[((size_t)3 * HIN + hb * KS + ki) * WIN + w];
        const int p = ki * KS + kj;
        e_lds[i] = (r + ab) * maskv[wb] * wkk[p] + bkk[p];
    }
    __syncthreads();
    // per-wb max (column max over ki, then across kj)
    if (tid < WIN) {
        float m = -INFINITY;
        #pragma unroll
        for (int ki = 0; ki < KS; ++ki) m = fmaxf(m, e_lds[ki * WIN + tid]);
        colsum[0][tid] = m;
    }
    __syncthreads();
    if (tid < WBL) {
        float m = -INFINITY;
        #pragma unroll
        for (int kj = 0; kj < KS; ++kj) m = fmaxf(m, colsum[0][tid * KS + kj]);
        wbmax[tid] = m;
    }
    __syncthreads();
    // exponentiate (unnormalized)
    for (int i = tid; i < KS * WIN; i += 256) {
        const int wb = (i % WIN) / KS;
        e_lds[i] = __expf(e_lds[i] - wbmax[wb]);
    }
    __syncthreads();
    // per-wb denominator
    if (tid < WIN) {
        float s = 0.f;
        #pragma unroll
        for (int ki = 0; ki < KS; ++ki) s += e_lds[ki * WIN + tid];
        colsum[0][tid] = s;
    }
    __syncthreads();
    if (tid < WBL) {
        float s = 0.f;
        #pragma unroll
        for (int kj = 0; kj < KS; ++kj) s += colsum[0][tid * KS + kj];
        wbsum[tid] = s;
    }
    __syncthreads();
    // weighted reduction over NC channels, one sync per channel (dbuf colsum)
    for (int n = 0; n < NC; ++n) {
        const int c = cg * NC + n;
        const float* hbase = hr_b + ((size_t)c * HIN + hb * KS) * WIN;
        if (tid < WIN) {
            float acc = 0.f;
            #pragma unroll
            for (int ki = 0; ki < KS; ++ki)
                acc += hbase[(size_t)ki * WIN + tid] * e_lds[ki * WIN + tid];
            colsum[n & 1][tid] = acc;
        }
        __syncthreads();
        if (tid < WBL) {
            float s = 0.f;
            #pragma unroll
            for (int kj = 0; kj < KS; ++kj) s += colsum[n & 1][tid * KS + kj];
            out_b[(size_t)c * (HB * WBL) + hb * WBL + tid] = s / wbsum[tid];
        }
    }
}

extern "C" void kernel_launch(void* const* d_in, const int* in_sizes, int n_in,
                              void* d_out, int out_size, void* d_ws, size_t ws_size,
                              hipStream_t stream) {
    const float* hr      = (const float*)d_in[0];  // (4,384,224,224)
    // d_in[1] = guidance (unused)
    const float* attn_w  = (const float*)d_in[2];  // (1,384)
    const float* attn_b  = (const float*)d_in[3];  // (1,)
    const float* w_kk    = (const float*)d_in[4];  // (14,14)
    const float* b_kk    = (const float*)d_in[5];  // (14,14)
    const int*   mask    = (const int*)d_in[6];    // (4,16,16,1) bool->int
    float* out = (float*)d_out;                    // (4,384,16,16)

    float* part = (float*)d_ws;                    // CG*HIN*WIN floats (802 KB)

    for (int b = 0; b < B; ++b) {
        const float* hr_b = hr + (size_t)b * C * HW;
        k_rowsum_b<<<HIN * CG, 256, 0, stream>>>(hr_b, attn_w, part);
        k_fused_b<<<HB * (C / NC), 256, 0, stream>>>(hr_b, part, attn_b, w_kk, b_kk,
                                                     mask + b * HB * WBL,
                                                     out + (size_t)b * C * HB * WBL);
    }
}

// Round 3
// 109.528 us; speedup vs baseline: 1.2349x; 1.2349x over previous
//
#include <hip/hip_runtime.h>
#include <math.h>

#define B 4
#define C 384
#define HIN 224
#define WIN 224
#define KS 14
#define HB 16
#define WBL 16
#define P 196        // KS*KS
#define HW (HIN * WIN)   // 50176
#define CG 2             // channel groups in gemv pass
#define CPG (C / CG)     // 192
#define NT 49            // hw tiles of 1024 floats per batch
#define NC 8             // channels per k3 block

// ---------------------------------------------------------------------------
// Kernel 1: GEMV-style partial rowsum.
// Block = (b, hw-tile of 1024 floats, channel-group of 192).
// Each thread owns one float4 of the tile, loops 192 channels (4KB/instr
// per-wave contiguous bursts), accumulates privately, writes partial plane.
// ---------------------------------------------------------------------------
__global__ __launch_bounds__(256) void k_gemv(const float* __restrict__ hr,
                                              const float* __restrict__ attn_w,
                                              float* __restrict__ part) {
    __shared__ float wlds[CPG];
    const int tid = threadIdx.x;
    const int cg = blockIdx.x & 1;
    const int t  = (blockIdx.x >> 1) % NT;
    const int b  = blockIdx.x / (2 * NT);
    if (tid < CPG) wlds[tid] = attn_w[cg * CPG + tid];
    __syncthreads();

    const float* base = hr + (size_t)(b * C + cg * CPG) * HW + t * 1024 + tid * 4;
    float4 acc = make_float4(0.f, 0.f, 0.f, 0.f);
    #pragma unroll 8
    for (int c = 0; c < CPG; ++c) {
        const float4 v = *reinterpret_cast<const float4*>(base + (size_t)c * HW);
        const float wc = wlds[c];
        acc.x += v.x * wc; acc.y += v.y * wc; acc.z += v.z * wc; acc.w += v.w * wc;
    }
    reinterpret_cast<float4*>(part + (size_t)(b * CG + cg) * HW + t * 1024)[tid] = acc;
}

// ---------------------------------------------------------------------------
// Kernel 2: logits -> softmax -> attn[b,hb,wb,p] (normalized).
// One block per (b,hb,wb). tid<196 handles one p. Sums the CG partials.
// ---------------------------------------------------------------------------
__global__ __launch_bounds__(256) void k_softmax(const float* __restrict__ part,
                                                 const float* __restrict__ attn_b,
                                                 const float* __restrict__ w_kk,
                                                 const float* __restrict__ b_kk,
                                                 const int* __restrict__ mask,
                                                 float* __restrict__ attn) {
    const int blk = blockIdx.x;        // 0 .. B*HB*WBL-1
    const int wb = blk % WBL;
    const int hb = (blk / WBL) % HB;
    const int b = blk / (WBL * HB);
    const int tid = threadIdx.x;

    float logit = 0.f;
    float l = -INFINITY;
    if (tid < P) {
        const int ki = tid / KS, kj = tid % KS;
        const size_t idx = (size_t)(hb * KS + ki) * WIN + wb * KS + kj;
        const float rv = part[(size_t)(b * CG + 0) * HW + idx]
                       + part[(size_t)(b * CG + 1) * HW + idx];
        const float m = mask[(b * HB + hb) * WBL + wb] ? 1.f : 0.f;
        logit = (rv + attn_b[0]) * m * w_kk[tid] + b_kk[tid];
        l = logit;
    }

    __shared__ float smax[4], ssum[4];
    float v = l;
    #pragma unroll
    for (int off = 32; off; off >>= 1) v = fmaxf(v, __shfl_xor(v, off));
    if ((tid & 63) == 0) smax[tid >> 6] = v;
    __syncthreads();
    const float bm = fmaxf(fmaxf(smax[0], smax[1]), fmaxf(smax[2], smax[3]));

    float e = (tid < P) ? __expf(logit - bm) : 0.f;
    float s = e;
    #pragma unroll
    for (int off = 32; off; off >>= 1) s += __shfl_xor(s, off);
    if ((tid & 63) == 0) ssum[tid >> 6] = s;
    __syncthreads();
    const float bs = ssum[0] + ssum[1] + ssum[2] + ssum[3];

    if (tid < P) attn[(size_t)blk * P + tid] = e / bs;
}

// ---------------------------------------------------------------------------
// Kernel 3: out[b,c,hb,wb] = sum_p hr_patch[p,c] * attn[b,hb,wb,p]
// One block per (b,hb, 8-channel group). Attn strip staged in LDS once
// (layout e_lds[ki][w], w = wb*14+kj), amortized over 8 channels.
// Per channel: tid<224 (ki0=tid/56, fc=tid%56) does float4 row-strided
// dot, then 4-group LDS reduce -> colsum[224], then kj-reduce -> 16 outs.
// ---------------------------------------------------------------------------
__global__ __launch_bounds__(256) void k_weighted(const float* __restrict__ hr,
                                                  const float* __restrict__ attn,
                                                  float* __restrict__ out) {
    __shared__ float e_lds[KS * WIN];     // 3136 floats
    __shared__ float4 red4[224];
    __shared__ float colsum[WIN];
    const int tid = threadIdx.x;
    const int cg = blockIdx.x % 48;           // channel group (fastest: attn L2 reuse)
    const int hb = (blockIdx.x / 48) & 15;
    const int b  = blockIdx.x / (48 * 16);

    const float* abase = attn + (size_t)((b * HB + hb) * WBL) * P;
    for (int i = tid; i < WBL * P; i += 256) {
        const int wb = i / P, p = i % P;
        e_lds[(p / KS) * WIN + wb * KS + (p % KS)] = abase[i];
    }
    __syncthreads();

    const int ki0 = tid / 56, fc = tid % 56;
    for (int n = 0; n < NC; ++n) {
        const int c = cg * NC + n;
        const float* hbase = hr + (size_t)((b * C + c) * HIN + hb * KS) * WIN;
        if (tid < 224) {
            float4 acc = make_float4(0.f, 0.f, 0.f, 0.f);
            #pragma unroll
            for (int r = ki0; r < KS; r += 4) {
                const float4 v = *reinterpret_cast<const float4*>(hbase + r * WIN + fc * 4);
                const float4 e = *reinterpret_cast<const float4*>(e_lds + r * WIN + fc * 4);
                acc.x += v.x * e.x; acc.y += v.y * e.y;
                acc.z += v.z * e.z; acc.w += v.w * e.w;
            }
            red4[tid] = acc;
        }
        __syncthreads();
        if (tid < 56) {
            const float4 a0 = red4[tid], a1 = red4[56 + tid],
                         a2 = red4[112 + tid], a3 = red4[168 + tid];
            reinterpret_cast<float4*>(colsum)[tid] = make_float4(
                a0.x + a1.x + a2.x + a3.x, a0.y + a1.y + a2.y + a3.y,
                a0.z + a1.z + a2.z + a3.z, a0.w + a1.w + a2.w + a3.w);
        }
        __syncthreads();
        if (tid < WBL) {
            float s = 0.f;
            #pragma unroll
            for (int kj = 0; kj < KS; ++kj) s += colsum[tid * KS + kj];
            out[(size_t)((b * C + c) * HB + hb) * WBL + tid] = s;
        }
    }
}

extern "C" void kernel_launch(void* const* d_in, const int* in_sizes, int n_in,
                              void* d_out, int out_size, void* d_ws, size_t ws_size,
                              hipStream_t stream) {
    const float* hr      = (const float*)d_in[0];  // (4,384,224,224)
    // d_in[1] = guidance (unused)
    const float* attn_w  = (const float*)d_in[2];  // (1,384)
    const float* attn_b  = (const float*)d_in[3];  // (1,)
    const float* w_kk    = (const float*)d_in[4];  // (14,14)
    const float* b_kk    = (const float*)d_in[5];  // (14,14)
    const int*   mask    = (const int*)d_in[6];    // (4,16,16,1) bool->int
    float* out = (float*)d_out;                    // (4,384,16,16)

    float* part = (float*)d_ws;                           // B*CG*HW floats (1.6MB)
    float* attn = part + (size_t)B * CG * HW;             // B*HB*WBL*P floats (802KB)

    k_gemv<<<B * NT * CG, 256, 0, stream>>>(hr, attn_w, part);
    k_softmax<<<B * HB * WBL, 256, 0, stream>>>(part, attn_b, w_kk, b_kk, mask, attn);
    k_weighted<<<B * 16 * 48, 256, 0, stream>>>(hr, attn, out);
}